// Round 11
// baseline (268.074 us; speedup 1.0000x reference)
//
#include <hip/hip_runtime.h>
#include <hip/hip_bf16.h>

#define HID1 16
#define NHEAD1 12
#define F1 (HID1*NHEAD1)   // 192
#define HID2 8
#define NHEAD2 8
#define F2 (HID2*NHEAD2)   // 64
#define NUM_FEA 213
#define NEG_SLOPE 0.2f
#define KP 224             // layer-1 K padded to 7*32 for MFMA
#define KP2 192            // layer-2 K (already 6*32)
#define LDK 40             // LDS k-stride (bf16 elems): 80B -> bank stride 20, 2-way max (free)
#define MR1 64             // gemm1 row tile (R18 win: 782 blocks, 23.3KB LDS)
#define MR2 64             // gemm2 row tile (R20)
#define NC1 224            // gemm1 output cols: 192 h + 12 as + 12 ad + 8 pad
#define NW2R 80            // Wt2 rows: 64 h + 8 as + 8 ad
#define SLOTS 56           // padded CSR row capacity (max degree ~38; 56 is safe)
// --- binned CSR build ---
#define BINS 256           // coarse bins over node space
#define NPB 196            // nodes per bin: 256*196 = 50176 >= 50000
#define CAP 4096           // bin capacity: Binomial mean 3332, sd 58 -> mean+13sd
#define FILLB 256          // proven R8/R10 config
#define EPT 13             // edges per thread: 256*256*13 = 851968 >= 850000

typedef __attribute__((ext_vector_type(8))) __bf16 bf16x8;
typedef __attribute__((ext_vector_type(4))) float floatx4;
typedef __attribute__((ext_vector_type(2))) float floatx2;
typedef float floatx4u __attribute__((ext_vector_type(4), aligned(4)));  // 4B-aligned vec load
typedef unsigned short ushort_t;

static __device__ __forceinline__ unsigned short f2bf(float f) {
    unsigned u = __float_as_uint(f);
    unsigned r = (u + 0x7fffu + ((u >> 16) & 1u)) >> 16;   // RNE
    return (unsigned short)r;
}
static __device__ __forceinline__ float lrelu(float e) {
    return e > 0.f ? e : NEG_SLOPE * e;
}
static __device__ __forceinline__ float elu(float v) {
    return v > 0.f ? v : (__expf(v) - 1.f);
}

// ---------------- prep: weight transforms || binned edge scatter (pass 1) -------

__global__ __launch_bounds__(256) void prep_kernel(
        const float* __restrict__ W1, const float* __restrict__ as1w,
        const float* __restrict__ ad1w, ushort_t* __restrict__ Wt1,
        const float* __restrict__ W2, const float* __restrict__ as2w,
        const float* __restrict__ ad2w, ushort_t* __restrict__ Wt2,
        const int* __restrict__ ei, int* __restrict__ binctr,
        unsigned* __restrict__ binbuf, int E, int Etot, int nwb) {
    int b = (int)blockIdx.x;
    int tid = threadIdx.x;
    if (b >= nwb) {
        // ---- binned scatter pass 1 ----
        __shared__ int hist[BINS];
        __shared__ int cur[BINS];
        int fb = b - nwb;
        if (tid < BINS) hist[tid] = 0;
        __syncthreads();
        unsigned stash[EPT];
        int base_e = fb * 256 + tid;
#pragma unroll
        for (int i = 0; i < EPT; i++) {
            int e = base_e + i * (FILLB * 256);
            unsigned pk = 0xffffffffu;                 // invalid marker (max valid 0xC34FC34F)
            if (e < Etot) {
                int s, d;
                if (e < E) { s = ei[e]; d = ei[E + e]; } else { s = e - E; d = s; }
                pk = (unsigned)s | ((unsigned)d << 16);
                atomicAdd(&hist[(unsigned)d / NPB], 1);
            }
            stash[i] = pk;
        }
        __syncthreads();
        if (tid < BINS) cur[tid] = atomicAdd(&binctr[tid], hist[tid]);  // global base
        __syncthreads();
#pragma unroll
        for (int i = 0; i < EPT; i++) {
            unsigned pk = stash[i];
            if (pk != 0xffffffffu) {
                int d = (int)(pk >> 16);
                int bin = (int)((unsigned)d / NPB);
                int dl = d - bin * NPB;
                int r = atomicAdd(&cur[bin], 1);       // LDS cursor holds global index
                if (r < CAP)
                    binbuf[(long)bin * CAP + r] = (pk & 0xffffu) | ((unsigned)dl << 16);
            }
        }
        return;
    }
    // ---- weight transforms + att-vector folds ----
    int j = b * 256 + tid;
    if (j < NC1 * KP) {
        int n = j / KP, k = j - n * KP;
        float v = 0.f;
        if (k < NUM_FEA) {
            if (n < 192) {
                v = W1[(long)k * F1 + n];
            } else if (n < 204) {
                int hd = n - 192;
                for (int c = 0; c < HID1; c++)
                    v += W1[(long)k * F1 + hd * HID1 + c] * as1w[hd * HID1 + c];
            } else if (n < 216) {
                int hd = n - 204;
                for (int c = 0; c < HID1; c++)
                    v += W1[(long)k * F1 + hd * HID1 + c] * ad1w[hd * HID1 + c];
            }
        }
        Wt1[j] = f2bf(v);
    } else {
        int j2 = j - NC1 * KP;
        if (j2 < NW2R * KP2) {
            int n = j2 / KP2, k = j2 - n * KP2;
            float v;
            if (n < 64) {
                v = W2[(long)k * F2 + n];
            } else if (n < 72) {
                int hd = n - 64;
                v = 0.f;
                for (int c = 0; c < HID2; c++)
                    v += W2[(long)k * F2 + hd * HID2 + c] * as2w[hd * HID2 + c];
            } else {
                int hd = n - 72;
                v = 0.f;
                for (int c = 0; c < HID2; c++)
                    v += W2[(long)k * F2 + hd * HID2 + c] * ad2w[hd * HID2 + c];
            }
            Wt2[j2] = f2bf(v);
        }
    }
}

// ---------------- combo: GEMM1 (64-row tile) || binsort pass 2 ----------------

static __device__ __forceinline__ void stageA(ushort_t* dst, const float* xp,
                                              bool ok, int col) {
    union { int4 q; ushort_t u[8]; } pk;
    if (ok && col + 8 <= NUM_FEA) {
        floatx4u a = *(const floatx4u*)(xp + col);
        floatx4u c = *(const floatx4u*)(xp + col + 4);
#pragma unroll
        for (int j = 0; j < 4; j++) { pk.u[j] = f2bf(a[j]); pk.u[4 + j] = f2bf(c[j]); }
    } else {
#pragma unroll
        for (int j = 0; j < 8; j++) {
            float v = (ok && col + j < NUM_FEA) ? xp[col + j] : 0.f;
            pk.u[j] = f2bf(v);
        }
    }
    *(int4*)dst = pk.q;
}

__global__ __launch_bounds__(256) void gemm1_bs_kernel(
        const float* __restrict__ X, const ushort_t* __restrict__ Wt,
        ushort_t* __restrict__ Hout, float* __restrict__ as_, float* __restrict__ ad_,
        const unsigned* __restrict__ binbuf, const int* __restrict__ binctr,
        ushort_t* __restrict__ esrcp, int* __restrict__ cnt,
        int N, int nblk_gemm) {
    __shared__ ushort_t As[MR1 * LDK];     // 5 KB
    __shared__ ushort_t Bs[NC1 * LDK];     // 17.5 KB
    __shared__ int lcnt[NPB];              // 784 B (binsort path)
    int tid = threadIdx.x;
    if ((int)blockIdx.x >= nblk_gemm) {
        // ---- binsort: per-bin LDS slot assignment ----
        int b = (int)blockIdx.x - nblk_gemm;
        if (tid < NPB) lcnt[tid] = 0;
        __syncthreads();
        int cntb = binctr[b];
        if (cntb > CAP) cntb = CAP;
        const unsigned* seg = binbuf + (long)b * CAP;
        for (int t = tid; t < cntb; t += 256) {
            unsigned u = seg[t];
            int s = (int)(u & 0xffffu);
            int dl = (int)(u >> 16);
            int slot = atomicAdd(&lcnt[dl], 1);
            if (slot < SLOTS)
                esrcp[(long)(b * NPB + dl) * SLOTS + slot] = (ushort_t)s;
        }
        __syncthreads();
        int d = b * NPB + tid;
        if (tid < NPB && d < N) cnt[d] = lcnt[tid];
        return;
    }
    int wave = tid >> 6, lane = tid & 63;
    int q = lane >> 4, l16 = lane & 15;
    int wm = (wave >> 1) * 32;
    int wn = (wave & 1) * 112;
    long row0 = (long)blockIdx.x * MR1;

    // A-staging: 64 rows x 4 chunks = 256 threads, exactly one chunk each
    int r0 = tid >> 2, ksl = (tid & 3) * 8;
    long gr0 = row0 + r0;
    bool ok0 = gr0 < N;
    const float* xp0 = X + gr0 * NUM_FEA;
    ushort_t* lds0 = &As[r0 * LDK + ksl];

    floatx4 acc[2][7] = {};

    for (int k0 = 0; k0 < KP; k0 += 32) {
        stageA(lds0, xp0, ok0, k0 + ksl);
#pragma unroll
        for (int p = 0; p < 4; p++) {
            int idx = p * 256 + tid;
            if (idx < NC1 * 4) {
                int r = idx >> 2, ks = (idx & 3) * 8;
                *(int4*)&Bs[r * LDK + ks] = *(const int4*)&Wt[(long)r * KP + k0 + ks];
            }
        }
        __syncthreads();
        bf16x8 af[2], bfr[7];
#pragma unroll
        for (int rt = 0; rt < 2; rt++)
            af[rt] = *(const bf16x8*)&As[(wm + rt * 16 + l16) * LDK + q * 8];
#pragma unroll
        for (int ct = 0; ct < 7; ct++)
            bfr[ct] = *(const bf16x8*)&Bs[(wn + ct * 16 + l16) * LDK + q * 8];
#pragma unroll
        for (int rt = 0; rt < 2; rt++)
#pragma unroll
            for (int ct = 0; ct < 7; ct++)
                acc[rt][ct] = __builtin_amdgcn_mfma_f32_16x16x32_bf16(af[rt], bfr[ct], acc[rt][ct], 0, 0, 0);
        __syncthreads();
    }
#pragma unroll
    for (int rt = 0; rt < 2; rt++) {
#pragma unroll
        for (int r = 0; r < 4; r++) {
            long grow = row0 + wm + rt * 16 + q * 4 + r;
            if (grow < N) {
#pragma unroll
                for (int ct = 0; ct < 7; ct++) {
                    int col = wn + ct * 16 + l16;
                    float v = acc[rt][ct][r];
                    if (col < 192)      Hout[grow * F1 + col] = f2bf(v);
                    else if (col < 204) as_[grow * NHEAD1 + col - 192] = v;
                    else if (col < 216) ad_[grow * NHEAD1 + col - 204] = v;
                }
            }
        }
    }
}

// ---------------- GEMM2 via MFMA bf16, att coeffs fused (64-row tile) -----------

__global__ __launch_bounds__(256) void gemm2_mfma(const ushort_t* __restrict__ Xbf,
                                                  const ushort_t* __restrict__ Wt,
                                                  ushort_t* __restrict__ Hout,
                                                  float* __restrict__ as_,
                                                  float* __restrict__ ad_, int N) {
    __shared__ ushort_t As[MR2 * LDK];     // 5 KB
    __shared__ ushort_t Bs[96 * LDK];      // 7.5 KB
    int tid = threadIdx.x;
    int wave = tid >> 6, lane = tid & 63;
    int q = lane >> 4, l16 = lane & 15;
    int wm = (wave >> 1) * 32;
    int wn = (wave & 1) * 48;
    long row0 = (long)blockIdx.x * MR2;

    // A-staging: 64 rows x 4 chunks = 256 threads, one int4 each
    int r0 = tid >> 2, ksl = (tid & 3) * 8;

    floatx4 acc[2][3] = {};

    for (int k0 = 0; k0 < KP2; k0 += 32) {
        *(int4*)&As[r0 * LDK + ksl] = *(const int4*)&Xbf[(row0 + r0) * KP2 + k0 + ksl];
#pragma unroll
        for (int p = 0; p < 2; p++) {
            int idx = p * 256 + tid;
            if (idx < 96 * 4) {
                int r = idx >> 2, ks = (idx & 3) * 8;
                int4 z = {0, 0, 0, 0};
                *(int4*)&Bs[r * LDK + ks] = (r < NW2R) ? *(const int4*)&Wt[(long)r * KP2 + k0 + ks] : z;
            }
        }
        __syncthreads();
        bf16x8 af[2], bfr[3];
#pragma unroll
        for (int rt = 0; rt < 2; rt++)
            af[rt] = *(const bf16x8*)&As[(wm + rt * 16 + l16) * LDK + q * 8];
#pragma unroll
        for (int ct = 0; ct < 3; ct++)
            bfr[ct] = *(const bf16x8*)&Bs[(wn + ct * 16 + l16) * LDK + q * 8];
#pragma unroll
        for (int rt = 0; rt < 2; rt++)
#pragma unroll
            for (int ct = 0; ct < 3; ct++)
                acc[rt][ct] = __builtin_amdgcn_mfma_f32_16x16x32_bf16(af[rt], bfr[ct], acc[rt][ct], 0, 0, 0);
        __syncthreads();
    }
#pragma unroll
    for (int rt = 0; rt < 2; rt++) {
#pragma unroll
        for (int r = 0; r < 4; r++) {
            long grow = row0 + wm + rt * 16 + q * 4 + r;
            if (grow < N) {
#pragma unroll
                for (int ct = 0; ct < 3; ct++) {
                    int col = wn + ct * 16 + l16;
                    float v = acc[rt][ct][r];
                    if (col < 64)      Hout[grow * F2 + col] = f2bf(v);
                    else if (col < 72) as_[grow * NHEAD2 + col - 64] = v;
                    else if (col < 80) ad_[grow * NHEAD2 + col - 72] = v;
                }
            }
        }
    }
}

// ---------------- gather layer 1: one wave/node, 8-edge chunks ---------
// R21: per-lane direct attention weights. Lane's head hj is FIXED, and s_e[i] is
// already in registers for the gather loads -> each lane computes its own
// w = exp(lrelu(as_[s*12+hj] + ad_[d*12+hj])) via one L2-resident scalar load
// (12 distinct addrs/wave, 4-lane broadcast). Deletes the w0/w1 shuffle
// choreography, its 2 serialized scalar loads, and the divergent i==5 straddle.

__global__ __launch_bounds__(256) void gather1_kernel(const int* __restrict__ cnt,
                                                      const ushort_t* __restrict__ esrcp,
                                                      const float* __restrict__ as_,
                                                      const float* __restrict__ ad_,
                                                      const ushort_t* __restrict__ h,
                                                      const float* __restrict__ bias,
                                                      ushort_t* __restrict__ xout, int N) {
    int d = blockIdx.x * 4 + (threadIdx.x >> 6);
    if (d >= N) return;
    int l = threadIdx.x & 63;
    int jc = l < 48 ? l : 47;
    int hj = jc >> 2;
    int deg = cnt[d]; if (deg > SLOTS) deg = SLOTS;
    int sfull = (int)esrcp[d * SLOTS + (l < SLOTS - 1 ? l : SLOTS - 1)];
    float advj = ad_[d * NHEAD1 + hj];
    float4 b4 = ((const float4*)bias)[jc];
    const char* hcol = (const char*)(h + 4 * jc);
    const float* asj = as_ + hj;

    floatx2 a01 = {0.f, 0.f}, a23 = {0.f, 0.f};
    float accd = 0.f;

    for (int p0 = 0; p0 < deg; p0 += 8) {
        int s_e[8];
#pragma unroll
        for (int i = 0; i < 8; i++) s_e[i] = __shfl(sfull, p0 + i, 64);
        uint2 g[8];
#pragma unroll
        for (int i = 0; i < 8; i++) {
            unsigned off = (unsigned)s_e[i] * (unsigned)(F1 * 2);
            g[i] = *(const uint2*)(hcol + off);
        }
        float w[8];
#pragma unroll
        for (int i = 0; i < 8; i++) {
            float av = asj[s_e[i] * NHEAD1];
            w[i] = (p0 + i < deg) ? __expf(lrelu(av + advj)) : 0.f;
        }
#pragma unroll
        for (int i = 0; i < 8; i++) {
            unsigned x = g[i].x, y = g[i].y;
            floatx2 h01, h23, w2;
            h01.x = __uint_as_float(x << 16);
            h01.y = __uint_as_float(x & 0xffff0000u);
            h23.x = __uint_as_float(y << 16);
            h23.y = __uint_as_float(y & 0xffff0000u);
            w2.x = w[i]; w2.y = w[i];
            a01 += w2 * h01;            // v_pk_fma_f32
            a23 += w2 * h23;
            accd += w[i];
        }
    }
    if (l < 48) {
        float inv = __builtin_amdgcn_rcpf(accd);
        float v0 = elu(a01.x * inv + b4.x);
        float v1 = elu(a01.y * inv + b4.y);
        float v2 = elu(a23.x * inv + b4.z);
        float v3 = elu(a23.y * inv + b4.w);
        uint2 outp;
        outp.x = (unsigned)f2bf(v0) | ((unsigned)f2bf(v1) << 16);
        outp.y = (unsigned)f2bf(v2) | ((unsigned)f2bf(v3) << 16);
        *(uint2*)(xout + (long)d * F1 + 4 * l) = outp;
    }
}

// ---------------- gather layer 2: one wave/node, 16-edge chunks ----------------

__global__ __launch_bounds__(256) void gather2_kernel(const int* __restrict__ cnt,
                                                      const ushort_t* __restrict__ esrcp,
                                                      const float* __restrict__ as_,
                                                      const float* __restrict__ ad_,
                                                      const ushort_t* __restrict__ h,
                                                      const float* __restrict__ bias,
                                                      float* __restrict__ xout, int N) {
    int d = blockIdx.x * 4 + (threadIdx.x >> 6);
    if (d >= N) return;
    int l = threadIdx.x & 63;
    int cg = l & 15;
    int hj = cg >> 1;
    int e_lo = l >> 4;
    int ie0 = l >> 3, hq = l & 7;
    int ie1 = 8 + ie0;
    int deg = cnt[d]; if (deg > SLOTS) deg = SLOTS;
    int sfull = (int)esrcp[d * SLOTS + (l < SLOTS - 1 ? l : SLOTS - 1)];
    float advq = ad_[d * NHEAD2 + hq];
    const char* hcol = (const char*)(h + 4 * cg);

    floatx2 a01 = {0.f, 0.f}, a23 = {0.f, 0.f};
    float accd = 0.f;

    for (int p0 = 0; p0 < deg; p0 += 16) {
        int se[4];
#pragma unroll
        for (int k = 0; k < 4; k++) se[k] = __shfl(sfull, p0 + e_lo + 4 * k, 64);
        uint2 g[4];
#pragma unroll
        for (int k = 0; k < 4; k++) {
            unsigned off = (unsigned)se[k] * (unsigned)(F2 * 2);
            g[k] = *(const uint2*)(hcol + off);
        }
        int sq0 = __shfl(sfull, p0 + ie0, 64);
        int sq1 = __shfl(sfull, p0 + ie1, 64);
        float a0v = as_[sq0 * NHEAD2 + hq];
        float a1v = as_[sq1 * NHEAD2 + hq];
        float w0d = (p0 + ie0 < deg) ? __expf(lrelu(a0v + advq)) : 0.f;
        float w1d = (p0 + ie1 < deg) ? __expf(lrelu(a1v + advq)) : 0.f;
#pragma unroll
        for (int k = 0; k < 4; k++) {
            int i = e_lo + 4 * k;
            float wk = (k < 2) ? __shfl(w0d, i * 8 + hj, 64)
                               : __shfl(w1d, i * 8 + hj - 64, 64);
            unsigned x = g[k].x, y = g[k].y;
            floatx2 h01, h23, w2;
            h01.x = __uint_as_float(x << 16);
            h01.y = __uint_as_float(x & 0xffff0000u);
            h23.x = __uint_as_float(y << 16);
            h23.y = __uint_as_float(y & 0xffff0000u);
            w2.x = wk; w2.y = wk;
            a01 += w2 * h01;
            a23 += w2 * h23;
            accd += wk;
        }
    }
    a01.x += __shfl_xor(a01.x, 16, 64); a01.x += __shfl_xor(a01.x, 32, 64);
    a01.y += __shfl_xor(a01.y, 16, 64); a01.y += __shfl_xor(a01.y, 32, 64);
    a23.x += __shfl_xor(a23.x, 16, 64); a23.x += __shfl_xor(a23.x, 32, 64);
    a23.y += __shfl_xor(a23.y, 16, 64); a23.y += __shfl_xor(a23.y, 32, 64);
    accd  += __shfl_xor(accd, 16, 64);  accd  += __shfl_xor(accd, 32, 64);
    if (l < 16) {
        float4 b4 = ((const float4*)bias)[cg];
        float inv = __builtin_amdgcn_rcpf(accd);
        float4 outp;
        outp.x = elu(a01.x * inv + b4.x);
        outp.y = elu(a01.y * inv + b4.y);
        outp.z = elu(a23.x * inv + b4.z);
        outp.w = elu(a23.y * inv + b4.w);
        *(float4*)(xout + (long)d * F2 + 4 * cg) = outp;
    }
}

// ---------------- pair predictor ----------------

__global__ void pair_kernel(const float* __restrict__ x, const int* __restrict__ n1,
                            const int* __restrict__ n2, const float* __restrict__ linW,
                            const float* __restrict__ linb, float* __restrict__ y, int P) {
    int idx = blockIdx.x * blockDim.x + threadIdx.x;
    if (idx >= P) return;
    const float4* xa = (const float4*)(x + (long)n1[idx] * F2);
    const float4* xb = (const float4*)(x + (long)n2[idx] * F2);
    float a0 = linb[0], a1 = linb[1];
#pragma unroll
    for (int k4 = 0; k4 < F2 / 4; k4++) {
        float4 v = xa[k4];
        int k = k4 * 4;
        a0 += v.x * linW[2 * k] + v.y * linW[2 * (k + 1)] + v.z * linW[2 * (k + 2)] + v.w * linW[2 * (k + 3)];
        a1 += v.x * linW[2 * k + 1] + v.y * linW[2 * (k + 1) + 1] + v.z * linW[2 * (k + 2) + 1] + v.w * linW[2 * (k + 3) + 1];
    }
#pragma unroll
    for (int k4 = 0; k4 < F2 / 4; k4++) {
        float4 v = xb[k4];
        int k = F2 + k4 * 4;
        a0 += v.x * linW[2 * k] + v.y * linW[2 * (k + 1)] + v.z * linW[2 * (k + 2)] + v.w * linW[2 * (k + 3)];
        a1 += v.x * linW[2 * k + 1] + v.y * linW[2 * (k + 1) + 1] + v.z * linW[2 * (k + 2) + 1] + v.w * linW[2 * (k + 3) + 1];
    }
    y[2 * idx]     = 1.f / (1.f + __expf(-a0));
    y[2 * idx + 1] = 1.f / (1.f + __expf(-a1));
}

// ---------------- launch ----------------

extern "C" void kernel_launch(void* const* d_in, const int* in_sizes, int n_in,
                              void* d_out, int out_size, void* d_ws, size_t ws_size,
                              hipStream_t stream) {
    const float* features = (const float*)d_in[0];
    const int*   ei       = (const int*)d_in[1];
    const int*   n1       = (const int*)d_in[2];
    const int*   n2       = (const int*)d_in[3];
    const float* W1       = (const float*)d_in[4];
    const float* att_s1   = (const float*)d_in[5];
    const float* att_d1   = (const float*)d_in[6];
    const float* b1       = (const float*)d_in[7];
    const float* W2       = (const float*)d_in[8];
    const float* att_s2   = (const float*)d_in[9];
    const float* att_d2   = (const float*)d_in[10];
    const float* b2       = (const float*)d_in[11];
    const float* linW     = (const float*)d_in[12];
    const float* linb     = (const float*)d_in[13];

    const int N = in_sizes[0] / NUM_FEA;      // 50000
    const int E = in_sizes[1] / 2;            // 800000
    const int P = in_sizes[2];                // 16384
    const int Etot = E + N;                   // 850000

    const int nblk1 = (N + MR1 - 1) / MR1;       // 782
    const int nblk2 = (N + MR2 - 1) / MR2;       // 782
    const int nwb = (NC1 * KP + NW2R * KP2 + 255) / 256;  // 256

    float* ws = (float*)d_ws;
    long o = 0;
    float* h1r  = ws + o; o += (long)N * F1 / 2;             // h1b bf16
    float* x1r  = ws + o; o += (long)N * F1 / 2;             // x1bf bf16
    float* as1  = ws + o; o += (long)N * NHEAD1;
    float* ad1  = ws + o; o += (long)N * NHEAD1;
    float* h2r  = ws + o; o += (long)N * F2 / 2;             // h2b bf16
    float* as2  = ws + o; o += (long)N * NHEAD2;
    float* ad2  = ws + o; o += (long)N * NHEAD2;
    float* w1r  = ws + o; o += ((long)NC1 * KP + 1) / 2;     // Wt1 bf16 (incl att cols)
    float* w2r  = ws + o; o += ((long)NW2R * KP2 + 1) / 2;   // Wt2 bf16 (incl att cols)
    float* esr  = ws + o; o += ((long)N * SLOTS + 1) / 2;    // esrc_pad ushort
    unsigned* binbuf = (unsigned*)(ws + o); o += (long)BINS * CAP;  // 4 MB
    int* binctr = (int*)(ws + o); o += BINS;
    int* cnt  = (int*)(ws + o); o += N;

    ushort_t* h1b   = (ushort_t*)h1r;
    ushort_t* x1bf  = (ushort_t*)x1r;
    ushort_t* h2b   = (ushort_t*)h2r;
    ushort_t* Wt1   = (ushort_t*)w1r;
    ushort_t* Wt2   = (ushort_t*)w2r;
    ushort_t* esrcp = (ushort_t*)esr;

    float* y_out = (float*)d_out;
    float* x_out = (float*)d_out + (long)2 * P;

    hipMemsetAsync(binctr, 0, (size_t)BINS * sizeof(int), stream);

    // prep: weight transforms || binned edge scatter pass 1
    prep_kernel<<<nwb + FILLB, 256, 0, stream>>>(
        W1, att_s1, att_d1, Wt1, W2, att_s2, att_d2, Wt2,
        ei, binctr, binbuf, E, Etot, nwb);

    // GEMM1 (64-row tile) || binsort pass 2
    gemm1_bs_kernel<<<nblk1 + BINS, 256, 0, stream>>>(
        features, Wt1, h1b, as1, ad1, binbuf, binctr, esrcp, cnt, N, nblk1);

    gather1_kernel<<<(N + 3) / 4, 256, 0, stream>>>(cnt, esrcp, as1, ad1, h1b, b1, x1bf, N);

    // layer 2
    gemm2_mfma<<<nblk2, 256, 0, stream>>>(x1bf, Wt2, h2b, as2, ad2, N);
    gather2_kernel<<<(N + 3) / 4, 256, 0, stream>>>(cnt, esrcp, as2, ad2, h2b, b2, x_out, N);

    // pair predictor
    pair_kernel<<<(P + 255) / 256, 256, 0, stream>>>(x_out, n1, n2, linW, linb, y_out, P);
}

// Round 12
// 249.101 us; speedup vs baseline: 1.0762x; 1.0762x over previous
//
#include <hip/hip_runtime.h>
#include <hip/hip_bf16.h>

#define HID1 16
#define NHEAD1 12
#define F1 (HID1*NHEAD1)   // 192
#define HID2 8
#define NHEAD2 8
#define F2 (HID2*NHEAD2)   // 64
#define NUM_FEA 213
#define NEG_SLOPE 0.2f
#define KP 224             // layer-1 K padded to 7*32 for MFMA
#define KP2 192            // layer-2 K (already 6*32)
#define LDK 40             // LDS k-stride (bf16 elems): 80B -> bank stride 20, 2-way max (free)
#define MR1 64             // gemm1 row tile (R18 win)
#define MR2 64             // gemm2 row tile (R20)
#define NC1 224            // gemm1 output cols: 192 h + 12 as + 12 ad + 8 pad
#define NW2R 80            // Wt2 rows: 64 h + 8 as + 8 ad
#define SLOTS 56           // padded CSR row capacity (max degree ~38; 56 is safe)
// --- binned CSR build ---
#define BINS 256           // coarse bins over node space
#define NPB 196            // nodes per bin: 256*196 = 50176 >= 50000
#define CAP 4096           // bin capacity: Binomial mean 3332, sd 58 -> mean+13sd
#define FILLB 256          // proven R8/R10 config
#define EPT 13             // edges per thread: 256*256*13 = 851968 >= 850000

typedef __attribute__((ext_vector_type(8))) __bf16 bf16x8;
typedef __attribute__((ext_vector_type(4))) float floatx4;
typedef __attribute__((ext_vector_type(2))) float floatx2;
typedef float floatx4u __attribute__((ext_vector_type(4), aligned(4)));  // 4B-aligned vec load
typedef unsigned short ushort_t;

static __device__ __forceinline__ unsigned short f2bf(float f) {
    unsigned u = __float_as_uint(f);
    unsigned r = (u + 0x7fffu + ((u >> 16) & 1u)) >> 16;   // RNE
    return (unsigned short)r;
}
static __device__ __forceinline__ float lrelu(float e) {
    return e > 0.f ? e : NEG_SLOPE * e;
}
static __device__ __forceinline__ float elu(float v) {
    return v > 0.f ? v : (__expf(v) - 1.f);
}

// ---------------- wprep: weight transforms + att-vector folds (tiny, ~3us) ------

__global__ __launch_bounds__(256) void wprep_kernel(
        const float* __restrict__ W1, const float* __restrict__ as1w,
        const float* __restrict__ ad1w, ushort_t* __restrict__ Wt1,
        const float* __restrict__ W2, const float* __restrict__ as2w,
        const float* __restrict__ ad2w, ushort_t* __restrict__ Wt2) {
    int j = blockIdx.x * 256 + threadIdx.x;
    if (j < NC1 * KP) {
        int n = j / KP, k = j - n * KP;
        float v = 0.f;
        if (k < NUM_FEA) {
            if (n < 192) {
                v = W1[(long)k * F1 + n];
            } else if (n < 204) {
                int hd = n - 192;
                for (int c = 0; c < HID1; c++)
                    v += W1[(long)k * F1 + hd * HID1 + c] * as1w[hd * HID1 + c];
            } else if (n < 216) {
                int hd = n - 204;
                for (int c = 0; c < HID1; c++)
                    v += W1[(long)k * F1 + hd * HID1 + c] * ad1w[hd * HID1 + c];
            }
        }
        Wt1[j] = f2bf(v);
    } else {
        int j2 = j - NC1 * KP;
        if (j2 < NW2R * KP2) {
            int n = j2 / KP2, k = j2 - n * KP2;
            float v;
            if (n < 64) {
                v = W2[(long)k * F2 + n];
            } else if (n < 72) {
                int hd = n - 64;
                v = 0.f;
                for (int c = 0; c < HID2; c++)
                    v += W2[(long)k * F2 + hd * HID2 + c] * as2w[hd * HID2 + c];
            } else {
                int hd = n - 72;
                v = 0.f;
                for (int c = 0; c < HID2; c++)
                    v += W2[(long)k * F2 + hd * HID2 + c] * ad2w[hd * HID2 + c];
            }
            Wt2[j2] = f2bf(v);
        }
    }
}

// ---------------- combo (R22): GEMM1 (64-row tile) || binned fill pass 1 --------
// gemm1 needs only Wt1 (wprep); fill needs only ei. Co-launching hides the
// ~45us fill under the GEMM instead of serializing before it. Combined LDS
// 25.3KB -> 6 blocks/CU, fill waves keep full latency hiding (NOT R3's 8%).

static __device__ __forceinline__ void stageA(ushort_t* dst, const float* xp,
                                              bool ok, int col) {
    union { int4 q; ushort_t u[8]; } pk;
    if (ok && col + 8 <= NUM_FEA) {
        floatx4u a = *(const floatx4u*)(xp + col);
        floatx4u c = *(const floatx4u*)(xp + col + 4);
#pragma unroll
        for (int j = 0; j < 4; j++) { pk.u[j] = f2bf(a[j]); pk.u[4 + j] = f2bf(c[j]); }
    } else {
#pragma unroll
        for (int j = 0; j < 8; j++) {
            float v = (ok && col + j < NUM_FEA) ? xp[col + j] : 0.f;
            pk.u[j] = f2bf(v);
        }
    }
    *(int4*)dst = pk.q;
}

__global__ __launch_bounds__(256) void gemm1_fill_kernel(
        const float* __restrict__ X, const ushort_t* __restrict__ Wt,
        ushort_t* __restrict__ Hout, float* __restrict__ as_, float* __restrict__ ad_,
        const int* __restrict__ ei, int* __restrict__ binctr,
        unsigned* __restrict__ binbuf, int E, int Etot,
        int N, int nblk_gemm) {
    __shared__ ushort_t As[MR1 * LDK];     // 5 KB
    __shared__ ushort_t Bs[NC1 * LDK];     // 17.5 KB
    __shared__ int hist[BINS];             // 1 KB (fill path)
    __shared__ int cur[BINS];              // 1 KB (fill path)
    int tid = threadIdx.x;
    if ((int)blockIdx.x >= nblk_gemm) {
        // ---- binned scatter pass 1 ----
        int fb = (int)blockIdx.x - nblk_gemm;
        if (tid < BINS) hist[tid] = 0;
        __syncthreads();
        unsigned stash[EPT];
        int base_e = fb * 256 + tid;
#pragma unroll
        for (int i = 0; i < EPT; i++) {
            int e = base_e + i * (FILLB * 256);
            unsigned pk = 0xffffffffu;                 // invalid marker
            if (e < Etot) {
                int s, d;
                if (e < E) { s = ei[e]; d = ei[E + e]; } else { s = e - E; d = s; }
                pk = (unsigned)s | ((unsigned)d << 16);
                atomicAdd(&hist[(unsigned)d / NPB], 1);
            }
            stash[i] = pk;
        }
        __syncthreads();
        if (tid < BINS) cur[tid] = atomicAdd(&binctr[tid], hist[tid]);  // global base
        __syncthreads();
#pragma unroll
        for (int i = 0; i < EPT; i++) {
            unsigned pk = stash[i];
            if (pk != 0xffffffffu) {
                int d = (int)(pk >> 16);
                int bin = (int)((unsigned)d / NPB);
                int dl = d - bin * NPB;
                int r = atomicAdd(&cur[bin], 1);       // LDS cursor holds global index
                if (r < CAP)
                    binbuf[(long)bin * CAP + r] = (pk & 0xffffu) | ((unsigned)dl << 16);
            }
        }
        return;
    }
    int wave = tid >> 6, lane = tid & 63;
    int q = lane >> 4, l16 = lane & 15;
    int wm = (wave >> 1) * 32;
    int wn = (wave & 1) * 112;
    long row0 = (long)blockIdx.x * MR1;

    // A-staging: 64 rows x 4 chunks = 256 threads, exactly one chunk each
    int r0 = tid >> 2, ksl = (tid & 3) * 8;
    long gr0 = row0 + r0;
    bool ok0 = gr0 < N;
    const float* xp0 = X + gr0 * NUM_FEA;
    ushort_t* lds0 = &As[r0 * LDK + ksl];

    floatx4 acc[2][7] = {};

    for (int k0 = 0; k0 < KP; k0 += 32) {
        stageA(lds0, xp0, ok0, k0 + ksl);
#pragma unroll
        for (int p = 0; p < 4; p++) {
            int idx = p * 256 + tid;
            if (idx < NC1 * 4) {
                int r = idx >> 2, ks = (idx & 3) * 8;
                *(int4*)&Bs[r * LDK + ks] = *(const int4*)&Wt[(long)r * KP + k0 + ks];
            }
        }
        __syncthreads();
        bf16x8 af[2], bfr[7];
#pragma unroll
        for (int rt = 0; rt < 2; rt++)
            af[rt] = *(const bf16x8*)&As[(wm + rt * 16 + l16) * LDK + q * 8];
#pragma unroll
        for (int ct = 0; ct < 7; ct++)
            bfr[ct] = *(const bf16x8*)&Bs[(wn + ct * 16 + l16) * LDK + q * 8];
#pragma unroll
        for (int rt = 0; rt < 2; rt++)
#pragma unroll
            for (int ct = 0; ct < 7; ct++)
                acc[rt][ct] = __builtin_amdgcn_mfma_f32_16x16x32_bf16(af[rt], bfr[ct], acc[rt][ct], 0, 0, 0);
        __syncthreads();
    }
#pragma unroll
    for (int rt = 0; rt < 2; rt++) {
#pragma unroll
        for (int r = 0; r < 4; r++) {
            long grow = row0 + wm + rt * 16 + q * 4 + r;
            if (grow < N) {
#pragma unroll
                for (int ct = 0; ct < 7; ct++) {
                    int col = wn + ct * 16 + l16;
                    float v = acc[rt][ct][r];
                    if (col < 192)      Hout[grow * F1 + col] = f2bf(v);
                    else if (col < 204) as_[grow * NHEAD1 + col - 192] = v;
                    else if (col < 216) ad_[grow * NHEAD1 + col - 204] = v;
                }
            }
        }
    }
}

// ---------------- binsort pass 2: per-bin LDS slot assignment (standalone) ------

__global__ __launch_bounds__(256) void binsort_kernel(
        const unsigned* __restrict__ binbuf, const int* __restrict__ binctr,
        ushort_t* __restrict__ esrcp, int* __restrict__ cnt, int N) {
    __shared__ int lcnt[NPB];
    int b = blockIdx.x, tid = threadIdx.x;
    if (tid < NPB) lcnt[tid] = 0;
    __syncthreads();
    int cntb = binctr[b];
    if (cntb > CAP) cntb = CAP;
    const unsigned* seg = binbuf + (long)b * CAP;
    for (int t = tid; t < cntb; t += 256) {
        unsigned u = seg[t];
        int s = (int)(u & 0xffffu);
        int dl = (int)(u >> 16);
        int slot = atomicAdd(&lcnt[dl], 1);
        if (slot < SLOTS)
            esrcp[(long)(b * NPB + dl) * SLOTS + slot] = (ushort_t)s;
    }
    __syncthreads();
    int d = b * NPB + tid;
    if (tid < NPB && d < N) cnt[d] = lcnt[tid];
}

// ---------------- GEMM2 via MFMA bf16, att coeffs fused (64-row tile) -----------

__global__ __launch_bounds__(256) void gemm2_mfma(const ushort_t* __restrict__ Xbf,
                                                  const ushort_t* __restrict__ Wt,
                                                  ushort_t* __restrict__ Hout,
                                                  float* __restrict__ as_,
                                                  float* __restrict__ ad_, int N) {
    __shared__ ushort_t As[MR2 * LDK];     // 5 KB
    __shared__ ushort_t Bs[96 * LDK];      // 7.5 KB
    int tid = threadIdx.x;
    int wave = tid >> 6, lane = tid & 63;
    int q = lane >> 4, l16 = lane & 15;
    int wm = (wave >> 1) * 32;
    int wn = (wave & 1) * 48;
    long row0 = (long)blockIdx.x * MR2;

    // A-staging: 64 rows x 4 chunks = 256 threads, one int4 each
    int r0 = tid >> 2, ksl = (tid & 3) * 8;

    floatx4 acc[2][3] = {};

    for (int k0 = 0; k0 < KP2; k0 += 32) {
        *(int4*)&As[r0 * LDK + ksl] = *(const int4*)&Xbf[(row0 + r0) * KP2 + k0 + ksl];
#pragma unroll
        for (int p = 0; p < 2; p++) {
            int idx = p * 256 + tid;
            if (idx < 96 * 4) {
                int r = idx >> 2, ks = (idx & 3) * 8;
                int4 z = {0, 0, 0, 0};
                *(int4*)&Bs[r * LDK + ks] = (r < NW2R) ? *(const int4*)&Wt[(long)r * KP2 + k0 + ks] : z;
            }
        }
        __syncthreads();
        bf16x8 af[2], bfr[3];
#pragma unroll
        for (int rt = 0; rt < 2; rt++)
            af[rt] = *(const bf16x8*)&As[(wm + rt * 16 + l16) * LDK + q * 8];
#pragma unroll
        for (int ct = 0; ct < 3; ct++)
            bfr[ct] = *(const bf16x8*)&Bs[(wn + ct * 16 + l16) * LDK + q * 8];
#pragma unroll
        for (int rt = 0; rt < 2; rt++)
#pragma unroll
            for (int ct = 0; ct < 3; ct++)
                acc[rt][ct] = __builtin_amdgcn_mfma_f32_16x16x32_bf16(af[rt], bfr[ct], acc[rt][ct], 0, 0, 0);
        __syncthreads();
    }
#pragma unroll
    for (int rt = 0; rt < 2; rt++) {
#pragma unroll
        for (int r = 0; r < 4; r++) {
            long grow = row0 + wm + rt * 16 + q * 4 + r;
            if (grow < N) {
#pragma unroll
                for (int ct = 0; ct < 3; ct++) {
                    int col = wn + ct * 16 + l16;
                    float v = acc[rt][ct][r];
                    if (col < 64)      Hout[grow * F2 + col] = f2bf(v);
                    else if (col < 72) as_[grow * NHEAD2 + col - 64] = v;
                    else if (col < 80) ad_[grow * NHEAD2 + col - 72] = v;
                }
            }
        }
    }
}

// ---------------- gather layer 1: one wave/node, 8-edge chunks ---------
// R22: reverted to R10's shuffle-choreography weights. R21's per-lane direct
// weights REGRESSED 56->79us: +5 VMEM/chunk on a latency-bound kernel
// (VALUBusy fell 58->52, HBM fell 45->32 — memory pressure, not VALU relief).

__global__ __launch_bounds__(256) void gather1_kernel(const int* __restrict__ cnt,
                                                      const ushort_t* __restrict__ esrcp,
                                                      const float* __restrict__ as_,
                                                      const float* __restrict__ ad_,
                                                      const ushort_t* __restrict__ h,
                                                      const float* __restrict__ bias,
                                                      ushort_t* __restrict__ xout, int N) {
    int d = blockIdx.x * 4 + (threadIdx.x >> 6);
    if (d >= N) return;
    int l = threadIdx.x & 63;
    int jc = l < 48 ? l : 47;
    int hj = jc >> 2;
    int e0 = l / 12, h0 = l - e0 * 12;
    int l64 = l + 64;
    int e1 = l64 / 12, h1 = l64 - e1 * 12;
    int deg = cnt[d]; if (deg > SLOTS) deg = SLOTS;
    int sfull = (int)esrcp[d * SLOTS + (l < SLOTS - 1 ? l : SLOTS - 1)];
    float adv0 = ad_[d * NHEAD1 + h0];
    float adv1 = ad_[d * NHEAD1 + h1];
    float4 b4 = ((const float4*)bias)[jc];
    const char* hcol = (const char*)(h + 4 * jc);

    floatx2 a01 = {0.f, 0.f}, a23 = {0.f, 0.f};
    float accd = 0.f;

    for (int p0 = 0; p0 < deg; p0 += 8) {
        int s_e[8];
#pragma unroll
        for (int i = 0; i < 8; i++) s_e[i] = __shfl(sfull, p0 + i, 64);
        uint2 g[8];
#pragma unroll
        for (int i = 0; i < 8; i++) {
            unsigned off = (unsigned)s_e[i] * (unsigned)(F1 * 2);
            g[i] = *(const uint2*)(hcol + off);
        }
        int sq0 = __shfl(sfull, p0 + e0, 64);
        int sq1 = __shfl(sfull, p0 + e1, 64);
        float a0v = as_[sq0 * NHEAD1 + h0];
        float a1v = as_[sq1 * NHEAD1 + h1];
        float w0 = (p0 + e0 < deg) ? __expf(lrelu(a0v + adv0)) : 0.f;
        float w1 = (e1 < 8 && p0 + e1 < deg) ? __expf(lrelu(a1v + adv1)) : 0.f;
#pragma unroll
        for (int i = 0; i < 8; i++) {
            float wi;
            if (i <= 4) {
                wi = __shfl(w0, i * 12 + hj, 64);
            } else if (i == 5) {
                float wa = __shfl(w0, 60 + hj, 64);
                int srcb = hj >= 4 ? hj - 4 : 0;
                float wb = __shfl(w1, srcb, 64);
                wi = (hj < 4) ? wa : wb;
            } else {
                wi = __shfl(w1, i * 12 + hj - 64, 64);
            }
            unsigned x = g[i].x, y = g[i].y;
            floatx2 h01, h23, w2;
            h01.x = __uint_as_float(x << 16);
            h01.y = __uint_as_float(x & 0xffff0000u);
            h23.x = __uint_as_float(y << 16);
            h23.y = __uint_as_float(y & 0xffff0000u);
            w2.x = wi; w2.y = wi;
            a01 += w2 * h01;            // v_pk_fma_f32
            a23 += w2 * h23;
            accd += wi;
        }
    }
    if (l < 48) {
        float inv = __builtin_amdgcn_rcpf(accd);
        float v0 = elu(a01.x * inv + b4.x);
        float v1 = elu(a01.y * inv + b4.y);
        float v2 = elu(a23.x * inv + b4.z);
        float v3 = elu(a23.y * inv + b4.w);
        uint2 outp;
        outp.x = (unsigned)f2bf(v0) | ((unsigned)f2bf(v1) << 16);
        outp.y = (unsigned)f2bf(v2) | ((unsigned)f2bf(v3) << 16);
        *(uint2*)(xout + (long)d * F1 + 4 * l) = outp;
    }
}

// ---------------- gather layer 2: one wave/node, 16-edge chunks ----------------

__global__ __launch_bounds__(256) void gather2_kernel(const int* __restrict__ cnt,
                                                      const ushort_t* __restrict__ esrcp,
                                                      const float* __restrict__ as_,
                                                      const float* __restrict__ ad_,
                                                      const ushort_t* __restrict__ h,
                                                      const float* __restrict__ bias,
                                                      float* __restrict__ xout, int N) {
    int d = blockIdx.x * 4 + (threadIdx.x >> 6);
    if (d >= N) return;
    int l = threadIdx.x & 63;
    int cg = l & 15;
    int hj = cg >> 1;
    int e_lo = l >> 4;
    int ie0 = l >> 3, hq = l & 7;
    int ie1 = 8 + ie0;
    int deg = cnt[d]; if (deg > SLOTS) deg = SLOTS;
    int sfull = (int)esrcp[d * SLOTS + (l < SLOTS - 1 ? l : SLOTS - 1)];
    float advq = ad_[d * NHEAD2 + hq];
    const char* hcol = (const char*)(h + 4 * cg);

    floatx2 a01 = {0.f, 0.f}, a23 = {0.f, 0.f};
    float accd = 0.f;

    for (int p0 = 0; p0 < deg; p0 += 16) {
        int se[4];
#pragma unroll
        for (int k = 0; k < 4; k++) se[k] = __shfl(sfull, p0 + e_lo + 4 * k, 64);
        uint2 g[4];
#pragma unroll
        for (int k = 0; k < 4; k++) {
            unsigned off = (unsigned)se[k] * (unsigned)(F2 * 2);
            g[k] = *(const uint2*)(hcol + off);
        }
        int sq0 = __shfl(sfull, p0 + ie0, 64);
        int sq1 = __shfl(sfull, p0 + ie1, 64);
        float a0v = as_[sq0 * NHEAD2 + hq];
        float a1v = as_[sq1 * NHEAD2 + hq];
        float w0d = (p0 + ie0 < deg) ? __expf(lrelu(a0v + advq)) : 0.f;
        float w1d = (p0 + ie1 < deg) ? __expf(lrelu(a1v + advq)) : 0.f;
#pragma unroll
        for (int k = 0; k < 4; k++) {
            int i = e_lo + 4 * k;
            float wk = (k < 2) ? __shfl(w0d, i * 8 + hj, 64)
                               : __shfl(w1d, i * 8 + hj - 64, 64);
            unsigned x = g[k].x, y = g[k].y;
            floatx2 h01, h23, w2;
            h01.x = __uint_as_float(x << 16);
            h01.y = __uint_as_float(x & 0xffff0000u);
            h23.x = __uint_as_float(y << 16);
            h23.y = __uint_as_float(y & 0xffff0000u);
            w2.x = wk; w2.y = wk;
            a01 += w2 * h01;
            a23 += w2 * h23;
            accd += wk;
        }
    }
    a01.x += __shfl_xor(a01.x, 16, 64); a01.x += __shfl_xor(a01.x, 32, 64);
    a01.y += __shfl_xor(a01.y, 16, 64); a01.y += __shfl_xor(a01.y, 32, 64);
    a23.x += __shfl_xor(a23.x, 16, 64); a23.x += __shfl_xor(a23.x, 32, 64);
    a23.y += __shfl_xor(a23.y, 16, 64); a23.y += __shfl_xor(a23.y, 32, 64);
    accd  += __shfl_xor(accd, 16, 64);  accd  += __shfl_xor(accd, 32, 64);
    if (l < 16) {
        float4 b4 = ((const float4*)bias)[cg];
        float inv = __builtin_amdgcn_rcpf(accd);
        float4 outp;
        outp.x = elu(a01.x * inv + b4.x);
        outp.y = elu(a01.y * inv + b4.y);
        outp.z = elu(a23.x * inv + b4.z);
        outp.w = elu(a23.y * inv + b4.w);
        *(float4*)(xout + (long)d * F2 + 4 * cg) = outp;
    }
}

// ---------------- pair predictor ----------------

__global__ void pair_kernel(const float* __restrict__ x, const int* __restrict__ n1,
                            const int* __restrict__ n2, const float* __restrict__ linW,
                            const float* __restrict__ linb, float* __restrict__ y, int P) {
    int idx = blockIdx.x * blockDim.x + threadIdx.x;
    if (idx >= P) return;
    const float4* xa = (const float4*)(x + (long)n1[idx] * F2);
    const float4* xb = (const float4*)(x + (long)n2[idx] * F2);
    float a0 = linb[0], a1 = linb[1];
#pragma unroll
    for (int k4 = 0; k4 < F2 / 4; k4++) {
        float4 v = xa[k4];
        int k = k4 * 4;
        a0 += v.x * linW[2 * k] + v.y * linW[2 * (k + 1)] + v.z * linW[2 * (k + 2)] + v.w * linW[2 * (k + 3)];
        a1 += v.x * linW[2 * k + 1] + v.y * linW[2 * (k + 1) + 1] + v.z * linW[2 * (k + 2) + 1] + v.w * linW[2 * (k + 3) + 1];
    }
#pragma unroll
    for (int k4 = 0; k4 < F2 / 4; k4++) {
        float4 v = xb[k4];
        int k = F2 + k4 * 4;
        a0 += v.x * linW[2 * k] + v.y * linW[2 * (k + 1)] + v.z * linW[2 * (k + 2)] + v.w * linW[2 * (k + 3)];
        a1 += v.x * linW[2 * k + 1] + v.y * linW[2 * (k + 1) + 1] + v.z * linW[2 * (k + 2) + 1] + v.w * linW[2 * (k + 3) + 1];
    }
    y[2 * idx]     = 1.f / (1.f + __expf(-a0));
    y[2 * idx + 1] = 1.f / (1.f + __expf(-a1));
}

// ---------------- launch ----------------

extern "C" void kernel_launch(void* const* d_in, const int* in_sizes, int n_in,
                              void* d_out, int out_size, void* d_ws, size_t ws_size,
                              hipStream_t stream) {
    const float* features = (const float*)d_in[0];
    const int*   ei       = (const int*)d_in[1];
    const int*   n1       = (const int*)d_in[2];
    const int*   n2       = (const int*)d_in[3];
    const float* W1       = (const float*)d_in[4];
    const float* att_s1   = (const float*)d_in[5];
    const float* att_d1   = (const float*)d_in[6];
    const float* b1       = (const float*)d_in[7];
    const float* W2       = (const float*)d_in[8];
    const float* att_s2   = (const float*)d_in[9];
    const float* att_d2   = (const float*)d_in[10];
    const float* b2       = (const float*)d_in[11];
    const float* linW     = (const float*)d_in[12];
    const float* linb     = (const float*)d_in[13];

    const int N = in_sizes[0] / NUM_FEA;      // 50000
    const int E = in_sizes[1] / 2;            // 800000
    const int P = in_sizes[2];                // 16384
    const int Etot = E + N;                   // 850000

    const int nblk1 = (N + MR1 - 1) / MR1;       // 782
    const int nblk2 = (N + MR2 - 1) / MR2;       // 782
    const int nwb = (NC1 * KP + NW2R * KP2 + 255) / 256;  // 256

    float* ws = (float*)d_ws;
    long o = 0;
    float* h1r  = ws + o; o += (long)N * F1 / 2;             // h1b bf16
    float* x1r  = ws + o; o += (long)N * F1 / 2;             // x1bf bf16
    float* as1  = ws + o; o += (long)N * NHEAD1;
    float* ad1  = ws + o; o += (long)N * NHEAD1;
    float* h2r  = ws + o; o += (long)N * F2 / 2;             // h2b bf16
    float* as2  = ws + o; o += (long)N * NHEAD2;
    float* ad2  = ws + o; o += (long)N * NHEAD2;
    float* w1r  = ws + o; o += ((long)NC1 * KP + 1) / 2;     // Wt1 bf16 (incl att cols)
    float* w2r  = ws + o; o += ((long)NW2R * KP2 + 1) / 2;   // Wt2 bf16 (incl att cols)
    float* esr  = ws + o; o += ((long)N * SLOTS + 1) / 2;    // esrc_pad ushort
    unsigned* binbuf = (unsigned*)(ws + o); o += (long)BINS * CAP;  // 4 MB
    int* binctr = (int*)(ws + o); o += BINS;
    int* cnt  = (int*)(ws + o); o += N;

    ushort_t* h1b   = (ushort_t*)h1r;
    ushort_t* x1bf  = (ushort_t*)x1r;
    ushort_t* h2b   = (ushort_t*)h2r;
    ushort_t* Wt1   = (ushort_t*)w1r;
    ushort_t* Wt2   = (ushort_t*)w2r;
    ushort_t* esrcp = (ushort_t*)esr;

    float* y_out = (float*)d_out;
    float* x_out = (float*)d_out + (long)2 * P;

    hipMemsetAsync(binctr, 0, (size_t)BINS * sizeof(int), stream);

    // wprep: tiny weight transform (feeds gemm1)
    wprep_kernel<<<nwb, 256, 0, stream>>>(W1, att_s1, att_d1, Wt1,
                                          W2, att_s2, att_d2, Wt2);

    // GEMM1 || binned fill pass 1 (fill hides under the GEMM)
    gemm1_fill_kernel<<<nblk1 + FILLB, 256, 0, stream>>>(
        features, Wt1, h1b, as1, ad1, ei, binctr, binbuf, E, Etot, N, nblk1);

    // binsort pass 2 (lightweight standalone)
    binsort_kernel<<<BINS, 256, 0, stream>>>(binbuf, binctr, esrcp, cnt, N);

    gather1_kernel<<<(N + 3) / 4, 256, 0, stream>>>(cnt, esrcp, as1, ad1, h1b, b1, x1bf, N);

    // layer 2
    gemm2_mfma<<<nblk2, 256, 0, stream>>>(x1bf, Wt2, h2b, as2, ad2, N);
    gather2_kernel<<<(N + 3) / 4, 256, 0, stream>>>(cnt, esrcp, as2, ad2, h2b, b2, x_out, N);

    // pair predictor
    pair_kernel<<<(P + 255) / 256, 256, 0, stream>>>(x_out, n1, n2, linW, linb, y_out, P);
}